// Round 18
// baseline (20178.207 us; speedup 1.0000x reference)
//
#include <hip/hip_runtime.h>
#include <cstdint>

#define TB 64      // batch
#define TC 64      // input channels
#define TT 1000    // timesteps
#define TH 512     // hidden
#define NCLS 5
#define NTHR 512
#define STEPS 1002 // s = 0..1001; layer l computes t = s - l

// LDS float offsets (ROUND-18: single-pass layout)
#define H0_OFF 0            // [16][512]
#define H1_OFF 8192
#define H2_OFF 16384
#define X_OFF  24576        // x tile [16 b][64 c], staged per step
#define SC_OFF 25600        // scratch: 8 waves x 1632 (l*544 + cl*68 + g + 4*b)
#define SC_W   1632
#define LDS_FLOATS (SC_OFF + 8 * SC_W)   // 38656
#define LDS_BYTES  (LDS_FLOATS * 4)      // 154624 (< 160 KiB, 1 block/CU)

__device__ __forceinline__ float sigf(float x) { return 1.0f / (1.0f + expf(-x)); }

// anti-remat pin, "+v" (round-15: "+a"/AGPR was a net loss)
__device__ __forceinline__ void pin4(float4& v) {
  asm volatile("" : "+v"(v.x), "+v"(v.y), "+v"(v.z), "+v"(v.w));
}

// ROUND-18 barrier: single-spin on ONE counter (drop the done->gen hop of
// round 17 — saves one L3 RTT on the critical path). Protocol otherwise
// round-16/17 proven: last-arriver-per-XCD does the ONE wbL2 (__threadfence)
// for its XCD, then bumps done; waiters spin done >= nxcd*t. Monotone
// counters, occupancy discovered at runtime (G16-safe). hbuf readers are
// L3-direct (sc0sc1) so no acquire is needed.
// Per-group bar layout (64 ints): [0]=disc cnt, [4]=disc gen, [8..15]=occ8,
// [16..23]=cntx, [32]=done.
__device__ __forceinline__ void group_barrier(int* gb, int s, unsigned xcc,
                                              int occ_mine, int nxcd) {
  __syncthreads();
  if (threadIdx.x == 0) {
    const int t = s + 1;
    int a = __hip_atomic_fetch_add(gb + 16 + xcc, 1, __ATOMIC_RELAXED, __HIP_MEMORY_SCOPE_AGENT);
    if (a == occ_mine * t - 1) {
      __threadfence();   // wbL2 of THIS XCD: covers every group block on it
      __hip_atomic_fetch_add(gb + 32, 1, __ATOMIC_RELAXED, __HIP_MEMORY_SCOPE_AGENT);
    }
    while (__hip_atomic_load(gb + 32, __ATOMIC_RELAXED, __HIP_MEMORY_SCOPE_AGENT) < nxcd * t)
      __builtin_amdgcn_s_sleep(1);
  }
  __syncthreads();
}

// fmaf dot4 as a function, NOT a macro (round-4 lesson).
__device__ __forceinline__ void dot4(float& acc, const float4 a, const float4 b) {
  acc = fmaf(a.x, b.x, acc); acc = fmaf(a.y, b.y, acc);
  acc = fmaf(a.z, b.z, acc); acc = fmaf(a.w, b.w, acc);
}

// direct global->LDS (16B/lane), L3-coherent read: aux=0x11 = SC0|SC1 cpol.
__device__ __forceinline__ void gload_lds16_cg(const char* gsrc_lane, char* lds_base) {
  __builtin_amdgcn_global_load_lds(
      (const __attribute__((address_space(1))) unsigned int*)gsrc_lane,
      (__attribute__((address_space(3))) unsigned int*)lds_base, 16, 0, 0x11);
}

// Persistent fused 3-layer LSTM (rounds 14-17 dataflow, proven exact).
// ROUND-18: single 16-batch compute pass (was 2x8): one scratch write, one
// sync, one reducer phase (384 threads / 6 waves, one output each — was two
// 192-thread phases). Per step: 7 syncthreads -> 5, one reducer tail not two.
// x staged per-step ([16][64], 4KB, cached line-reused loads) to make room
// for the doubled scratch (LDS total 154624 B < previous 158720).
__global__ __launch_bounds__(NTHR) __attribute__((amdgpu_waves_per_eu(2, 2)))
void lstm_pipe(
    const float* __restrict__ x, const float* __restrict__ Wih0,
    const float* __restrict__ WihR, const float* __restrict__ Whh,
    const float* __restrict__ bih, const float* __restrict__ bhh,
    float* __restrict__ hbuf, int* __restrict__ bar)
{
  __shared__ float lds[LDS_FLOATS];
  const int tid = threadIdx.x;
  const int blk = blockIdx.x;
  const int grp = blk >> 6, slot = blk & 63;
  const int b_base = grp * 16;
  const int kk = tid >> 5;          // 0..15 K-slice
  const int rt = tid & 31;
  const int g  = rt & 3;            // gate i,f,g,o
  const int cl = rt >> 2;           // 0..7 local cell
  const int cell = slot * 8 + cl;
  const int row  = g * TH + cell;   // gate-row in [2048]
  const int wv = tid >> 6;          // wave 0..7
  const int lane = tid & 63;

  int* gb = bar + grp * 64;         // per-group barrier state (64 ints)

  // ---- weights -> registers (164 floats), pinned ----
  float4 wx, wh0[8], w1a[8], w1b[8], w2a[8], w2b[8];
  wx = *(const float4*)(Wih0 + (size_t)row * TC + 4 * kk);
  pin4(wx);
  {
    const float* p0 = Whh  + (size_t)row * TH + 32 * kk;            // Whh[0]
    const float* p1 = WihR + (size_t)row * TH + 32 * kk;            // Wih[1]
    const float* p2 = Whh  + (size_t)(2048 + row) * TH + 32 * kk;   // Whh[1]
    const float* p3 = WihR + (size_t)(2048 + row) * TH + 32 * kk;   // Wih[2]
    const float* p4 = Whh  + (size_t)(4096 + row) * TH + 32 * kk;   // Whh[2]
#pragma unroll
    for (int i = 0; i < 8; ++i) {
      wh0[i] = *(const float4*)(p0 + 4 * i); pin4(wh0[i]);
      w1a[i] = *(const float4*)(p1 + 4 * i); pin4(w1a[i]);
      w1b[i] = *(const float4*)(p2 + 4 * i); pin4(w1b[i]);
      w2a[i] = *(const float4*)(p3 + 4 * i); pin4(w2a[i]);
      w2b[i] = *(const float4*)(p4 + 4 * i); pin4(w2b[i]);
    }
  }

  // ---- reducer setup (tid<384: one (layer rl, cell rc, batch rb)) ----
  const int rl = tid >> 7;          // 0..2 when tid<384
  const int ridx = tid & 127;
  const int rc = ridx >> 4;         // 0..7
  const int rb = ridx & 15;         // 0..15
  const int rcell = slot * 8 + rc;
  float4 bias_r = make_float4(0.f, 0.f, 0.f, 0.f);
  if (tid < 384) {
    bias_r.x = bih[rl * 2048 + rcell]        + bhh[rl * 2048 + rcell];
    bias_r.y = bih[rl * 2048 +  512 + rcell] + bhh[rl * 2048 +  512 + rcell];
    bias_r.z = bih[rl * 2048 + 1024 + rcell] + bhh[rl * 2048 + 1024 + rcell];
    bias_r.w = bih[rl * 2048 + 1536 + rcell] + bhh[rl * 2048 + 1536 + rcell];
  }
  float cst = 0.f;                  // cell state (one (l,c,b) per reducer thread)

  // ---- occupancy discovery (once; blocks never migrate CUs/XCDs) ----
  unsigned xcc = 0;
  int occ_mine = 0, nxcd = 0;
  if (tid == 0) {
    unsigned xr;
    asm volatile("s_getreg_b32 %0, hwreg(HW_REG_XCC_ID)" : "=s"(xr));
    xcc = xr & 7;
    __hip_atomic_fetch_add(gb + 8 + xcc, 1, __ATOMIC_RELAXED, __HIP_MEMORY_SCOPE_AGENT);
    int a = __hip_atomic_fetch_add(gb + 0, 1, __ATOMIC_RELAXED, __HIP_MEMORY_SCOPE_AGENT);
    if (a == 63)
      __hip_atomic_fetch_add(gb + 4, 1, __ATOMIC_RELAXED, __HIP_MEMORY_SCOPE_AGENT);
    while (__hip_atomic_load(gb + 4, __ATOMIC_RELAXED, __HIP_MEMORY_SCOPE_AGENT) < 1)
      __builtin_amdgcn_s_sleep(1);
#pragma unroll
    for (int i = 0; i < 8; ++i) {
      int o = __hip_atomic_load(gb + 8 + i, __ATOMIC_RELAXED, __HIP_MEMORY_SCOPE_AGENT);
      if (i == (int)xcc) occ_mine = o;
      if (o > 0) ++nxcd;
    }
  }
  __syncthreads();

  for (int s = 0; s < STEPS; ++s) {
    // ---------- stage tiles ----------
    {
      const bool v0 = (s >= 1 && s <= 1000);   // h0(s-1)
      const bool v1 = (s >= 2);                // h1(s-2)
      const bool v2 = (s >= 3);                // h2(s-3)
      if (v0) {
        const char* gp = (const char*)(hbuf + ((size_t)(0 + ((s - 1) & 1)) * TB + b_base) * TH);
        char* lb = (char*)lds + H0_OFF * 4;
#pragma unroll
        for (int i = 0; i < 4; ++i) {
          int off = wv * 4096 + i * 1024;
          gload_lds16_cg(gp + off + lane * 16, lb + off);
        }
      }
      if (v1) {
        const char* gp = (const char*)(hbuf + ((size_t)(2 + ((s - 2) & 1)) * TB + b_base) * TH);
        char* lb = (char*)lds + H1_OFF * 4;
#pragma unroll
        for (int i = 0; i < 4; ++i) {
          int off = wv * 4096 + i * 1024;
          gload_lds16_cg(gp + off + lane * 16, lb + off);
        }
      }
      if (v2) {
        const char* gp = (const char*)(hbuf + ((size_t)(4 + ((s - 3) & 1)) * TB + b_base) * TH);
        char* lb = (char*)lds + H2_OFF * 4;
#pragma unroll
        for (int i = 0; i < 4; ++i) {
          int off = wv * 4096 + i * 1024;
          gload_lds16_cg(gp + off + lane * 16, lb + off);
        }
      }
      if (s <= 999) {   // x tile [16][64] at time s (plain cached, line-reused)
        const int e0 = tid, e1 = tid + NTHR;
        float xs0 = x[(size_t)(b_base + (e0 >> 6)) * (TC * TT) + (size_t)(e0 & 63) * TT + s];
        float xs1 = x[(size_t)(b_base + (e1 >> 6)) * (TC * TT) + (size_t)(e1 & 63) * TT + s];
        lds[X_OFF + e0] = xs0;
        lds[X_OFF + e1] = xs1;
      }
    }
    __syncthreads();

    // ---------- compute: single pass, 16 batches ----------
    {
      float a0[16], a1[16], a2[16];
#pragma unroll
      for (int b = 0; b < 16; ++b) { a0[b] = 0.f; a1[b] = 0.f; a2[b] = 0.f; }
#pragma unroll
      for (int b = 0; b < 16; ++b) {
        if (s <= 999) {
          float4 xf = *(const float4*)(lds + X_OFF + b * TC + 4 * kk);
          dot4(a0[b], wx, xf);
        }
        if (s >= 1 && s <= 1000) {
          const float* hb = lds + H0_OFF + b * TH + 32 * kk;
#pragma unroll
          for (int c4 = 0; c4 < 2; ++c4) {
            float4 f0 = *(const float4*)(hb + 16 * c4 + 0);
            float4 f1 = *(const float4*)(hb + 16 * c4 + 4);
            float4 f2 = *(const float4*)(hb + 16 * c4 + 8);
            float4 f3 = *(const float4*)(hb + 16 * c4 + 12);
            if (s <= 999) {
              dot4(a0[b], wh0[4 * c4 + 0], f0); dot4(a0[b], wh0[4 * c4 + 1], f1);
              dot4(a0[b], wh0[4 * c4 + 2], f2); dot4(a0[b], wh0[4 * c4 + 3], f3);
            }
            dot4(a1[b], w1a[4 * c4 + 0], f0); dot4(a1[b], w1a[4 * c4 + 1], f1);
            dot4(a1[b], w1a[4 * c4 + 2], f2); dot4(a1[b], w1a[4 * c4 + 3], f3);
          }
        }
        if (s >= 2) {
          const float* hb = lds + H1_OFF + b * TH + 32 * kk;
#pragma unroll
          for (int c4 = 0; c4 < 2; ++c4) {
            float4 f0 = *(const float4*)(hb + 16 * c4 + 0);
            float4 f1 = *(const float4*)(hb + 16 * c4 + 4);
            float4 f2 = *(const float4*)(hb + 16 * c4 + 8);
            float4 f3 = *(const float4*)(hb + 16 * c4 + 12);
            if (s <= 1000) {
              dot4(a1[b], w1b[4 * c4 + 0], f0); dot4(a1[b], w1b[4 * c4 + 1], f1);
              dot4(a1[b], w1b[4 * c4 + 2], f2); dot4(a1[b], w1b[4 * c4 + 3], f3);
            }
            dot4(a2[b], w2a[4 * c4 + 0], f0); dot4(a2[b], w2a[4 * c4 + 1], f1);
            dot4(a2[b], w2a[4 * c4 + 2], f2); dot4(a2[b], w2a[4 * c4 + 3], f3);
          }
        }
        if (s >= 3) {
          const float* hb = lds + H2_OFF + b * TH + 32 * kk;
#pragma unroll
          for (int c4 = 0; c4 < 2; ++c4) {
            float4 f0 = *(const float4*)(hb + 16 * c4 + 0);
            float4 f1 = *(const float4*)(hb + 16 * c4 + 4);
            float4 f2 = *(const float4*)(hb + 16 * c4 + 8);
            float4 f3 = *(const float4*)(hb + 16 * c4 + 12);
            dot4(a2[b], w2b[4 * c4 + 0], f0); dot4(a2[b], w2b[4 * c4 + 1], f1);
            dot4(a2[b], w2b[4 * c4 + 2], f2); dot4(a2[b], w2b[4 * c4 + 3], f3);
          }
        }
      }
      // kk-pair reduce (lane ^ 32), then LDS scratch (32-bank conflict-free)
#pragma unroll
      for (int b = 0; b < 16; ++b) {
        a0[b] += __shfl_xor(a0[b], 32, 64);
        a1[b] += __shfl_xor(a1[b], 32, 64);
        a2[b] += __shfl_xor(a2[b], 32, 64);
      }
      if ((tid & 32) == 0) {
        float* sb = lds + SC_OFF + wv * SC_W + cl * 68 + g;
#pragma unroll
        for (int b = 0; b < 16; ++b) {
          sb[4 * b]        = a0[b];
          sb[544 + 4 * b]  = a1[b];
          sb[1088 + 4 * b] = a2[b];
        }
      }
    }
    __syncthreads();

    // ---------- pointwise: 384 threads, one (l,c,b) each ----------
    if (tid < 384) {
      const int tl = s - rl;
      if (tl >= 0 && tl < TT) {
        float sx = 0.f, sy = 0.f, sz = 0.f, sw = 0.f;
        const float* sbr = lds + SC_OFF + rl * 544 + rc * 68 + 4 * rb;
#pragma unroll
        for (int w8 = 0; w8 < 8; ++w8) {
          float4 v = *(const float4*)(sbr + w8 * SC_W);
          sx += v.x; sy += v.y; sz += v.z; sw += v.w;
        }
        float ii = sigf(sx + bias_r.x);
        float ff = sigf(sy + bias_r.y);
        float gg = tanhf(sz + bias_r.z);
        float oo = sigf(sw + bias_r.w);
        float cc = (tl == 0) ? ii * gg : fmaf(ff, cst, ii * gg);
        cst = cc;
        float hh = oo * tanhf(cc);
        hbuf[((size_t)(rl * 2 + (tl & 1)) * TB + b_base + rb) * TH + rcell] = hh;
      }
    }
    group_barrier(gb, s, xcc, occ_mine, nxcd);
  }
}

__global__ void fc_kernel(const float* __restrict__ hbuf, const float* __restrict__ Wfc,
                          const float* __restrict__ bfc, float* __restrict__ out) {
  int bb = blockIdx.x, lane = threadIdx.x;
  const float* h = hbuf + ((size_t)5 * TB + bb) * TH;   // layer2, parity (999&1)=1
  for (int n = 0; n < NCLS; ++n) {
    float s = 0.f;
    for (int k = lane; k < TH; k += 64) s = fmaf(h[k], Wfc[n * TH + k], s);
    for (int off = 32; off > 0; off >>= 1) s += __shfl_down(s, off, 64);
    if (lane == 0) out[bb * NCLS + n] = s + bfc[n];
  }
}

extern "C" void kernel_launch(void* const* d_in, const int* in_sizes, int n_in,
                              void* d_out, int out_size, void* d_ws, size_t ws_size,
                              hipStream_t stream) {
  const float* x    = (const float*)d_in[0];
  const float* Wih0 = (const float*)d_in[1];
  const float* WihR = (const float*)d_in[2];
  const float* Whh  = (const float*)d_in[3];
  const float* bih  = (const float*)d_in[4];
  const float* bhh  = (const float*)d_in[5];
  const float* Wfc  = (const float*)d_in[6];
  const float* bfc  = (const float*)d_in[7];
  float* out = (float*)d_out;

  char* ws = (char*)d_ws;
  int*   bar  = (int*)ws;                             // 1 KB: 4 groups x 64 ints
  float* hbuf = (float*)(ws + 1024);                  // [3][2][64][512] = 768 KB
  // total d_ws use: 769 KB

  hipMemsetAsync(bar, 0, 1024, stream);
  lstm_pipe<<<256, NTHR, 0, stream>>>(x, Wih0, WihR, Whh, bih, bhh, hbuf, bar);
  fc_kernel<<<TB, 64, 0, stream>>>(hbuf, Wfc, bfc, out);
}

// Round 19
// 16805.603 us; speedup vs baseline: 1.2007x; 1.2007x over previous
//
#include <hip/hip_runtime.h>
#include <cstdint>

#define TB 64      // batch
#define TC 64      // input channels
#define TT 1000    // timesteps
#define TH 512     // hidden
#define NCLS 5
#define NTHR 512
#define STEPS 1002 // s = 0..1001; layer l computes t = s - l

// LDS float offsets (round-17 proven layout)
#define H0_OFF 0            // [16][512]
#define H1_OFF 8192
#define H2_OFF 16384
#define X_OFF  24576        // x chunk: [8 t][16 b][64 c]
#define SC_OFF 32768        // scratch: 8 waves x 864 (l*288 + cl*36 + 4b + g)
#define SC_W   864
#define LDS_FLOATS (SC_OFF + 8 * SC_W)   // 39680
#define LDS_BYTES  (LDS_FLOATS * 4)      // 158720  (fits 160 KiB, 1 block/CU)

__device__ __forceinline__ float sigf(float x) { return 1.0f / (1.0f + expf(-x)); }

// anti-remat pin, "+v" (round-15: "+a"/AGPR was a net loss)
__device__ __forceinline__ void pin4(float4& v) {
  asm volatile("" : "+v"(v.x), "+v"(v.y), "+v"(v.z), "+v"(v.w));
}

// ROUND-19 barrier: round-17 protocol with the round-18 one-hop spin.
// (Round 18 bundled this with a single-pass compute that spilled 48 accs ->
// +416MB/dispatch scratch writes, +3ms. This round isolates the barrier win.)
// last-arriver-per-XCD does the ONE wbL2 (__threadfence) for its XCD, bumps
// done; waiters spin done >= nxcd*t directly (no done->gen hop). Monotone
// counters, occupancy discovered at runtime (G16-safe). hbuf readers are
// L3-direct (sc0sc1) so no acquire fence is needed.
// Per-group bar layout (64 ints): [0]=disc cnt, [4]=disc gen, [8..15]=occ8,
// [16..23]=cntx, [32]=done.
__device__ __forceinline__ void group_barrier(int* gb, int s, unsigned xcc,
                                              int occ_mine, int nxcd) {
  __syncthreads();
  if (threadIdx.x == 0) {
    const int t = s + 1;
    int a = __hip_atomic_fetch_add(gb + 16 + xcc, 1, __ATOMIC_RELAXED, __HIP_MEMORY_SCOPE_AGENT);
    if (a == occ_mine * t - 1) {
      __threadfence();   // wbL2 of THIS XCD: covers every group block on it
      __hip_atomic_fetch_add(gb + 32, 1, __ATOMIC_RELAXED, __HIP_MEMORY_SCOPE_AGENT);
    }
    while (__hip_atomic_load(gb + 32, __ATOMIC_RELAXED, __HIP_MEMORY_SCOPE_AGENT) < nxcd * t)
      __builtin_amdgcn_s_sleep(1);
  }
  __syncthreads();
}

// fmaf dot4 as a function, NOT a macro (round-4 lesson).
__device__ __forceinline__ void dot4(float& acc, const float4 a, const float4 b) {
  acc = fmaf(a.x, b.x, acc); acc = fmaf(a.y, b.y, acc);
  acc = fmaf(a.z, b.z, acc); acc = fmaf(a.w, b.w, acc);
}

// direct global->LDS (16B/lane), L3-coherent read: aux=0x11 = SC0|SC1 cpol.
__device__ __forceinline__ void gload_lds16_cg(const char* gsrc_lane, char* lds_base) {
  __builtin_amdgcn_global_load_lds(
      (const __attribute__((address_space(1))) unsigned int*)gsrc_lane,
      (__attribute__((address_space(3))) unsigned int*)lds_base, 16, 0, 0x11);
}

// Persistent fused 3-layer LSTM — round-17 compute structure (proven 17.2ms,
// exact): 2 passes x 8 batches (24 live accs fits the hard 128-VGPR cap;
// round 18's 1x16-batch pass spilled), x staged in 8-step chunks, h tiles
// L3-direct into static LDS. 256 blocks = 4 groups x 64 slots; slot owns
// cells [slot*8,slot*8+8) in all 3 layers; layer l computes t = s-l.
__global__ __launch_bounds__(NTHR) __attribute__((amdgpu_waves_per_eu(2, 2)))
void lstm_pipe(
    const float* __restrict__ x, const float* __restrict__ Wih0,
    const float* __restrict__ WihR, const float* __restrict__ Whh,
    const float* __restrict__ bih, const float* __restrict__ bhh,
    float* __restrict__ hbuf, int* __restrict__ bar)
{
  __shared__ float lds[LDS_FLOATS];
  const int tid = threadIdx.x;
  const int blk = blockIdx.x;
  const int grp = blk >> 6, slot = blk & 63;
  const int b_base = grp * 16;
  const int kk = tid >> 5;          // 0..15 K-slice
  const int rt = tid & 31;
  const int g  = rt & 3;            // gate i,f,g,o
  const int cl = rt >> 2;           // 0..7 local cell
  const int cell = slot * 8 + cl;
  const int row  = g * TH + cell;   // gate-row in [2048]
  const int wv = tid >> 6;          // wave 0..7
  const int lane = tid & 63;

  int* gb = bar + grp * 64;         // per-group barrier state (64 ints)

  // ---- weights -> registers (164 floats), pinned ----
  float4 wx, wh0[8], w1a[8], w1b[8], w2a[8], w2b[8];
  wx = *(const float4*)(Wih0 + (size_t)row * TC + 4 * kk);
  pin4(wx);
  {
    const float* p0 = Whh  + (size_t)row * TH + 32 * kk;            // Whh[0]
    const float* p1 = WihR + (size_t)row * TH + 32 * kk;            // Wih[1]
    const float* p2 = Whh  + (size_t)(2048 + row) * TH + 32 * kk;   // Whh[1]
    const float* p3 = WihR + (size_t)(2048 + row) * TH + 32 * kk;   // Wih[2]
    const float* p4 = Whh  + (size_t)(4096 + row) * TH + 32 * kk;   // Whh[2]
#pragma unroll
    for (int i = 0; i < 8; ++i) {
      wh0[i] = *(const float4*)(p0 + 4 * i); pin4(wh0[i]);
      w1a[i] = *(const float4*)(p1 + 4 * i); pin4(w1a[i]);
      w1b[i] = *(const float4*)(p2 + 4 * i); pin4(w1b[i]);
      w2a[i] = *(const float4*)(p3 + 4 * i); pin4(w2a[i]);
      w2b[i] = *(const float4*)(p4 + 4 * i); pin4(w2b[i]);
    }
  }

  // ---- reducer setup (tid<192: one (layer rl, cell rc, batch rb)) ----
  const int rl = tid >> 6;          // 0..2 when tid<192
  const int rc = (tid & 63) >> 3;   // 0..7
  const int rb = tid & 7;           // 0..7 (batch within pass)
  const int rcell = slot * 8 + rc;
  float4 bias_r = make_float4(0.f, 0.f, 0.f, 0.f);
  if (tid < 192) {
    bias_r.x = bih[rl * 2048 + rcell]        + bhh[rl * 2048 + rcell];
    bias_r.y = bih[rl * 2048 +  512 + rcell] + bhh[rl * 2048 +  512 + rcell];
    bias_r.z = bih[rl * 2048 + 1024 + rcell] + bhh[rl * 2048 + 1024 + rcell];
    bias_r.w = bih[rl * 2048 + 1536 + rcell] + bhh[rl * 2048 + 1536 + rcell];
  }
  float cst0 = 0.f, cst1 = 0.f;     // cell state (pass 0 / pass 1 batch)

  // ---- occupancy discovery (once; blocks never migrate CUs/XCDs) ----
  unsigned xcc = 0;
  int occ_mine = 0, nxcd = 0;
  if (tid == 0) {
    unsigned xr;
    asm volatile("s_getreg_b32 %0, hwreg(HW_REG_XCC_ID)" : "=s"(xr));
    xcc = xr & 7;
    __hip_atomic_fetch_add(gb + 8 + xcc, 1, __ATOMIC_RELAXED, __HIP_MEMORY_SCOPE_AGENT);
    int a = __hip_atomic_fetch_add(gb + 0, 1, __ATOMIC_RELAXED, __HIP_MEMORY_SCOPE_AGENT);
    if (a == 63)
      __hip_atomic_fetch_add(gb + 4, 1, __ATOMIC_RELAXED, __HIP_MEMORY_SCOPE_AGENT);
    while (__hip_atomic_load(gb + 4, __ATOMIC_RELAXED, __HIP_MEMORY_SCOPE_AGENT) < 1)
      __builtin_amdgcn_s_sleep(1);
#pragma unroll
    for (int i = 0; i < 8; ++i) {
      int o = __hip_atomic_load(gb + 8 + i, __ATOMIC_RELAXED, __HIP_MEMORY_SCOPE_AGENT);
      if (i == (int)xcc) occ_mine = o;
      if (o > 0) ++nxcd;
    }
  }
  __syncthreads();

  for (int s = 0; s < STEPS; ++s) {
    // ---------- stage tiles ----------
    {
      const bool v0 = (s >= 1 && s <= 1000);       // h0(s-1)
      const bool v1 = (s >= 2);                    // h1(s-2)
      const bool v2 = (s >= 3);                    // h2(s-3)
      const bool vc = ((s & 7) == 0 && s <= 999);  // x chunk [s, s+8)
      if (v0) {
        const char* gp = (const char*)(hbuf + ((size_t)(0 + ((s - 1) & 1)) * TB + b_base) * TH);
        char* lb = (char*)lds + H0_OFF * 4;
#pragma unroll
        for (int i = 0; i < 4; ++i) {
          int off = wv * 4096 + i * 1024;
          gload_lds16_cg(gp + off + lane * 16, lb + off);
        }
      }
      if (v1) {
        const char* gp = (const char*)(hbuf + ((size_t)(2 + ((s - 2) & 1)) * TB + b_base) * TH);
        char* lb = (char*)lds + H1_OFF * 4;
#pragma unroll
        for (int i = 0; i < 4; ++i) {
          int off = wv * 4096 + i * 1024;
          gload_lds16_cg(gp + off + lane * 16, lb + off);
        }
      }
      if (v2) {
        const char* gp = (const char*)(hbuf + ((size_t)(4 + ((s - 3) & 1)) * TB + b_base) * TH);
        char* lb = (char*)lds + H2_OFF * 4;
#pragma unroll
        for (int i = 0; i < 4; ++i) {
          int off = wv * 4096 + i * 1024;
          gload_lds16_cg(gp + off + lane * 16, lb + off);
        }
      }
      if (vc) {   // 8 timesteps of x for (b,c) pairs e0=tid, e1=tid+512 (plain cached)
        const int e0 = tid, e1 = tid + NTHR;
        const float* q0 = x + (size_t)(b_base + (e0 >> 6)) * (TC * TT) + (size_t)(e0 & 63) * TT + s;
        const float* q1 = x + (size_t)(b_base + (e1 >> 6)) * (TC * TT) + (size_t)(e1 & 63) * TT + s;
        float4 xa0 = *(const float4*)(q0), xa1 = *(const float4*)(q0 + 4);
        float4 xb0 = *(const float4*)(q1), xb1 = *(const float4*)(q1 + 4);
        float* d0 = lds + X_OFF + (e0 >> 6) * 64 + (e0 & 63);
        float* d1 = lds + X_OFF + (e1 >> 6) * 64 + (e1 & 63);
        d0[0 * 1024] = xa0.x; d0[1 * 1024] = xa0.y; d0[2 * 1024] = xa0.z; d0[3 * 1024] = xa0.w;
        d0[4 * 1024] = xa1.x; d0[5 * 1024] = xa1.y; d0[6 * 1024] = xa1.z; d0[7 * 1024] = xa1.w;
        d1[0 * 1024] = xb0.x; d1[1 * 1024] = xb0.y; d1[2 * 1024] = xb0.z; d1[3 * 1024] = xb0.w;
        d1[4 * 1024] = xb1.x; d1[5 * 1024] = xb1.y; d1[6 * 1024] = xb1.z; d1[7 * 1024] = xb1.w;
      }
    }
    __syncthreads();

    // ---------- compute: 2 passes of 8 batches ----------
#pragma unroll
    for (int p = 0; p < 2; ++p) {
      float a0[8], a1[8], a2[8];
#pragma unroll
      for (int b = 0; b < 8; ++b) { a0[b] = 0.f; a1[b] = 0.f; a2[b] = 0.f; }
#pragma unroll
      for (int b = 0; b < 8; ++b) {
        const int bb = p * 8 + b;
        if (s <= 999) {
          float4 xf = *(const float4*)(lds + X_OFF + (s & 7) * 1024 + bb * 64 + 4 * kk);
          dot4(a0[b], wx, xf);
        }
        if (s >= 1 && s <= 1000) {
          const float* hb = lds + H0_OFF + bb * TH + 32 * kk;
#pragma unroll
          for (int c4 = 0; c4 < 2; ++c4) {
            float4 f0 = *(const float4*)(hb + 16 * c4 + 0);
            float4 f1 = *(const float4*)(hb + 16 * c4 + 4);
            float4 f2 = *(const float4*)(hb + 16 * c4 + 8);
            float4 f3 = *(const float4*)(hb + 16 * c4 + 12);
            if (s <= 999) {
              dot4(a0[b], wh0[4 * c4 + 0], f0); dot4(a0[b], wh0[4 * c4 + 1], f1);
              dot4(a0[b], wh0[4 * c4 + 2], f2); dot4(a0[b], wh0[4 * c4 + 3], f3);
            }
            dot4(a1[b], w1a[4 * c4 + 0], f0); dot4(a1[b], w1a[4 * c4 + 1], f1);
            dot4(a1[b], w1a[4 * c4 + 2], f2); dot4(a1[b], w1a[4 * c4 + 3], f3);
          }
        }
        if (s >= 2) {
          const float* hb = lds + H1_OFF + bb * TH + 32 * kk;
#pragma unroll
          for (int c4 = 0; c4 < 2; ++c4) {
            float4 f0 = *(const float4*)(hb + 16 * c4 + 0);
            float4 f1 = *(const float4*)(hb + 16 * c4 + 4);
            float4 f2 = *(const float4*)(hb + 16 * c4 + 8);
            float4 f3 = *(const float4*)(hb + 16 * c4 + 12);
            if (s <= 1000) {
              dot4(a1[b], w1b[4 * c4 + 0], f0); dot4(a1[b], w1b[4 * c4 + 1], f1);
              dot4(a1[b], w1b[4 * c4 + 2], f2); dot4(a1[b], w1b[4 * c4 + 3], f3);
            }
            dot4(a2[b], w2a[4 * c4 + 0], f0); dot4(a2[b], w2a[4 * c4 + 1], f1);
            dot4(a2[b], w2a[4 * c4 + 2], f2); dot4(a2[b], w2a[4 * c4 + 3], f3);
          }
        }
        if (s >= 3) {
          const float* hb = lds + H2_OFF + bb * TH + 32 * kk;
#pragma unroll
          for (int c4 = 0; c4 < 2; ++c4) {
            float4 f0 = *(const float4*)(hb + 16 * c4 + 0);
            float4 f1 = *(const float4*)(hb + 16 * c4 + 4);
            float4 f2 = *(const float4*)(hb + 16 * c4 + 8);
            float4 f3 = *(const float4*)(hb + 16 * c4 + 12);
            dot4(a2[b], w2b[4 * c4 + 0], f0); dot4(a2[b], w2b[4 * c4 + 1], f1);
            dot4(a2[b], w2b[4 * c4 + 2], f2); dot4(a2[b], w2b[4 * c4 + 3], f3);
          }
        }
      }
      // kk-pair reduce (lane ^ 32), then LDS scratch (conflict-free stride 36)
#pragma unroll
      for (int b = 0; b < 8; ++b) {
        a0[b] += __shfl_xor(a0[b], 32, 64);
        a1[b] += __shfl_xor(a1[b], 32, 64);
        a2[b] += __shfl_xor(a2[b], 32, 64);
      }
      if ((tid & 32) == 0) {
        float* sb = lds + SC_OFF + wv * SC_W + cl * 36 + g;
#pragma unroll
        for (int b = 0; b < 8; ++b) {
          sb[4 * b]       = a0[b];
          sb[288 + 4 * b] = a1[b];
          sb[576 + 4 * b] = a2[b];
        }
      }
      __syncthreads();
      if (tid < 192) {
        const int tl = s - rl;
        if (tl >= 0 && tl < TT) {
          float sx = 0.f, sy = 0.f, sz = 0.f, sw = 0.f;
          const float* sb = lds + SC_OFF + rl * 288 + rc * 36 + 4 * rb;
#pragma unroll
          for (int w8 = 0; w8 < 8; ++w8) {
            float4 v = *(const float4*)(sb + w8 * SC_W);
            sx += v.x; sy += v.y; sz += v.z; sw += v.w;
          }
          float ii = sigf(sx + bias_r.x);
          float ff = sigf(sy + bias_r.y);
          float gg = tanhf(sz + bias_r.z);
          float oo = sigf(sw + bias_r.w);
          float cprev = p ? cst1 : cst0;
          float cc = (tl == 0) ? ii * gg : fmaf(ff, cprev, ii * gg);
          if (p) cst1 = cc; else cst0 = cc;
          float hh = oo * tanhf(cc);
          hbuf[((size_t)(rl * 2 + (tl & 1)) * TB + b_base + p * 8 + rb) * TH + rcell] = hh;
        }
      }
      __syncthreads();
    }
    group_barrier(gb, s, xcc, occ_mine, nxcd);
  }
}

__global__ void fc_kernel(const float* __restrict__ hbuf, const float* __restrict__ Wfc,
                          const float* __restrict__ bfc, float* __restrict__ out) {
  int bb = blockIdx.x, lane = threadIdx.x;
  const float* h = hbuf + ((size_t)5 * TB + bb) * TH;   // layer2, parity (999&1)=1
  for (int n = 0; n < NCLS; ++n) {
    float s = 0.f;
    for (int k = lane; k < TH; k += 64) s = fmaf(h[k], Wfc[n * TH + k], s);
    for (int off = 32; off > 0; off >>= 1) s += __shfl_down(s, off, 64);
    if (lane == 0) out[bb * NCLS + n] = s + bfc[n];
  }
}

extern "C" void kernel_launch(void* const* d_in, const int* in_sizes, int n_in,
                              void* d_out, int out_size, void* d_ws, size_t ws_size,
                              hipStream_t stream) {
  const float* x    = (const float*)d_in[0];
  const float* Wih0 = (const float*)d_in[1];
  const float* WihR = (const float*)d_in[2];
  const float* Whh  = (const float*)d_in[3];
  const float* bih  = (const float*)d_in[4];
  const float* bhh  = (const float*)d_in[5];
  const float* Wfc  = (const float*)d_in[6];
  const float* bfc  = (const float*)d_in[7];
  float* out = (float*)d_out;

  char* ws = (char*)d_ws;
  int*   bar  = (int*)ws;                             // 1 KB: 4 groups x 64 ints
  float* hbuf = (float*)(ws + 1024);                  // [3][2][64][512] = 768 KB
  // total d_ws use: 769 KB

  hipMemsetAsync(bar, 0, 1024, stream);
  lstm_pipe<<<256, NTHR, 0, stream>>>(x, Wih0, WihR, Whh, bih, bhh, hbuf, bar);
  fc_kernel<<<TB, 64, 0, stream>>>(hbuf, Wfc, bfc, out);
}

// Round 20
// 16418.069 us; speedup vs baseline: 1.2290x; 1.0236x over previous
//
#include <hip/hip_runtime.h>
#include <cstdint>

#define TB 64      // batch
#define TC 64      // input channels
#define TT 1000    // timesteps
#define TH 512     // hidden
#define NCLS 5
#define NTHR 512
#define STEPS 1002 // s = 0..1001; layer l computes t = s - l

// LDS float offsets (round-17 proven layout)
#define H0_OFF 0            // [16][512]
#define H1_OFF 8192
#define H2_OFF 16384
#define X_OFF  24576        // x chunk: [8 t][16 b][64 c]
#define SC_OFF 32768        // scratch: 8 waves x 864 (l*288 + cl*36 + 4b + g)
#define SC_W   864
#define LDS_FLOATS (SC_OFF + 8 * SC_W)   // 39680
#define LDS_BYTES  (LDS_FLOATS * 4)      // 158720  (fits 160 KiB, 1 block/CU)

__device__ __forceinline__ float sigf(float x) { return 1.0f / (1.0f + expf(-x)); }

// ROUND-20: pin4 REMOVED. A/B ledger: pins were added in round 12 (25.0->25.5,
// never a win) and all barrier gains since were measured only on the pinned
// build. Pinning under the immovable 128-VGPR cap forces ~75 floats/thread to
// scratch (L2 footprint ~5MB/XCD > 4MB L2 -> thrash); unpinned remat reloads
// the SHARED weights (2.6MB/XCD, L2-resident since the release-only barrier
// stopped invalidating L2). Remat is numerically identical.

// ROUND-19 barrier (proven): last-arriver-per-XCD does the ONE wbL2
// (__threadfence) for its XCD, bumps done; waiters spin done >= nxcd*t
// directly. Monotone counters, occupancy discovered at runtime (G16-safe).
// hbuf readers are L3-direct (sc0sc1) so no acquire fence is needed.
// Per-group bar layout (64 ints): [0]=disc cnt, [4]=disc gen, [8..15]=occ8,
// [16..23]=cntx, [32]=done.
__device__ __forceinline__ void group_barrier(int* gb, int s, unsigned xcc,
                                              int occ_mine, int nxcd) {
  __syncthreads();
  if (threadIdx.x == 0) {
    const int t = s + 1;
    int a = __hip_atomic_fetch_add(gb + 16 + xcc, 1, __ATOMIC_RELAXED, __HIP_MEMORY_SCOPE_AGENT);
    if (a == occ_mine * t - 1) {
      __threadfence();   // wbL2 of THIS XCD: covers every group block on it
      __hip_atomic_fetch_add(gb + 32, 1, __ATOMIC_RELAXED, __HIP_MEMORY_SCOPE_AGENT);
    }
    while (__hip_atomic_load(gb + 32, __ATOMIC_RELAXED, __HIP_MEMORY_SCOPE_AGENT) < nxcd * t)
      __builtin_amdgcn_s_sleep(1);
  }
  __syncthreads();
}

// fmaf dot4 as a function, NOT a macro (round-4 lesson).
__device__ __forceinline__ void dot4(float& acc, const float4 a, const float4 b) {
  acc = fmaf(a.x, b.x, acc); acc = fmaf(a.y, b.y, acc);
  acc = fmaf(a.z, b.z, acc); acc = fmaf(a.w, b.w, acc);
}

// direct global->LDS (16B/lane), L3-coherent read: aux=0x11 = SC0|SC1 cpol.
__device__ __forceinline__ void gload_lds16_cg(const char* gsrc_lane, char* lds_base) {
  __builtin_amdgcn_global_load_lds(
      (const __attribute__((address_space(1))) unsigned int*)gsrc_lane,
      (__attribute__((address_space(3))) unsigned int*)lds_base, 16, 0, 0x11);
}

// Persistent fused 3-layer LSTM — round-19 structure (proven 16.8ms, exact):
// 2 passes x 8 batches, x staged in 8-step chunks, h tiles L3-direct into
// static LDS. 256 blocks = 4 groups x 64 slots; slot owns cells
// [slot*8,slot*8+8) in all 3 layers; layer l computes t = s-l.
__global__ __launch_bounds__(NTHR) __attribute__((amdgpu_waves_per_eu(2, 2)))
void lstm_pipe(
    const float* __restrict__ x, const float* __restrict__ Wih0,
    const float* __restrict__ WihR, const float* __restrict__ Whh,
    const float* __restrict__ bih, const float* __restrict__ bhh,
    float* __restrict__ hbuf, int* __restrict__ bar)
{
  __shared__ float lds[LDS_FLOATS];
  const int tid = threadIdx.x;
  const int blk = blockIdx.x;
  const int grp = blk >> 6, slot = blk & 63;
  const int b_base = grp * 16;
  const int kk = tid >> 5;          // 0..15 K-slice
  const int rt = tid & 31;
  const int g  = rt & 3;            // gate i,f,g,o
  const int cl = rt >> 2;           // 0..7 local cell
  const int cell = slot * 8 + cl;
  const int row  = g * TH + cell;   // gate-row in [2048]
  const int wv = tid >> 6;          // wave 0..7
  const int lane = tid & 63;

  int* gb = bar + grp * 64;         // per-group barrier state (64 ints)

  // ---- weights -> registers/remat (164 floats; unpinned: compiler chooses
  //      live-in-VGPR vs reload-from-L2 per value) ----
  float4 wx, wh0[8], w1a[8], w1b[8], w2a[8], w2b[8];
  wx = *(const float4*)(Wih0 + (size_t)row * TC + 4 * kk);
  {
    const float* p0 = Whh  + (size_t)row * TH + 32 * kk;            // Whh[0]
    const float* p1 = WihR + (size_t)row * TH + 32 * kk;            // Wih[1]
    const float* p2 = Whh  + (size_t)(2048 + row) * TH + 32 * kk;   // Whh[1]
    const float* p3 = WihR + (size_t)(2048 + row) * TH + 32 * kk;   // Wih[2]
    const float* p4 = Whh  + (size_t)(4096 + row) * TH + 32 * kk;   // Whh[2]
#pragma unroll
    for (int i = 0; i < 8; ++i) {
      wh0[i] = *(const float4*)(p0 + 4 * i);
      w1a[i] = *(const float4*)(p1 + 4 * i);
      w1b[i] = *(const float4*)(p2 + 4 * i);
      w2a[i] = *(const float4*)(p3 + 4 * i);
      w2b[i] = *(const float4*)(p4 + 4 * i);
    }
  }

  // ---- reducer setup (tid<192: one (layer rl, cell rc, batch rb)) ----
  const int rl = tid >> 6;          // 0..2 when tid<192
  const int rc = (tid & 63) >> 3;   // 0..7
  const int rb = tid & 7;           // 0..7 (batch within pass)
  const int rcell = slot * 8 + rc;
  float4 bias_r = make_float4(0.f, 0.f, 0.f, 0.f);
  if (tid < 192) {
    bias_r.x = bih[rl * 2048 + rcell]        + bhh[rl * 2048 + rcell];
    bias_r.y = bih[rl * 2048 +  512 + rcell] + bhh[rl * 2048 +  512 + rcell];
    bias_r.z = bih[rl * 2048 + 1024 + rcell] + bhh[rl * 2048 + 1024 + rcell];
    bias_r.w = bih[rl * 2048 + 1536 + rcell] + bhh[rl * 2048 + 1536 + rcell];
  }
  float cst0 = 0.f, cst1 = 0.f;     // cell state (pass 0 / pass 1 batch)

  // ---- occupancy discovery (once; blocks never migrate CUs/XCDs) ----
  unsigned xcc = 0;
  int occ_mine = 0, nxcd = 0;
  if (tid == 0) {
    unsigned xr;
    asm volatile("s_getreg_b32 %0, hwreg(HW_REG_XCC_ID)" : "=s"(xr));
    xcc = xr & 7;
    __hip_atomic_fetch_add(gb + 8 + xcc, 1, __ATOMIC_RELAXED, __HIP_MEMORY_SCOPE_AGENT);
    int a = __hip_atomic_fetch_add(gb + 0, 1, __ATOMIC_RELAXED, __HIP_MEMORY_SCOPE_AGENT);
    if (a == 63)
      __hip_atomic_fetch_add(gb + 4, 1, __ATOMIC_RELAXED, __HIP_MEMORY_SCOPE_AGENT);
    while (__hip_atomic_load(gb + 4, __ATOMIC_RELAXED, __HIP_MEMORY_SCOPE_AGENT) < 1)
      __builtin_amdgcn_s_sleep(1);
#pragma unroll
    for (int i = 0; i < 8; ++i) {
      int o = __hip_atomic_load(gb + 8 + i, __ATOMIC_RELAXED, __HIP_MEMORY_SCOPE_AGENT);
      if (i == (int)xcc) occ_mine = o;
      if (o > 0) ++nxcd;
    }
  }
  __syncthreads();

  for (int s = 0; s < STEPS; ++s) {
    // ---------- stage tiles ----------
    {
      const bool v0 = (s >= 1 && s <= 1000);       // h0(s-1)
      const bool v1 = (s >= 2);                    // h1(s-2)
      const bool v2 = (s >= 3);                    // h2(s-3)
      const bool vc = ((s & 7) == 0 && s <= 999);  // x chunk [s, s+8)
      if (v0) {
        const char* gp = (const char*)(hbuf + ((size_t)(0 + ((s - 1) & 1)) * TB + b_base) * TH);
        char* lb = (char*)lds + H0_OFF * 4;
#pragma unroll
        for (int i = 0; i < 4; ++i) {
          int off = wv * 4096 + i * 1024;
          gload_lds16_cg(gp + off + lane * 16, lb + off);
        }
      }
      if (v1) {
        const char* gp = (const char*)(hbuf + ((size_t)(2 + ((s - 2) & 1)) * TB + b_base) * TH);
        char* lb = (char*)lds + H1_OFF * 4;
#pragma unroll
        for (int i = 0; i < 4; ++i) {
          int off = wv * 4096 + i * 1024;
          gload_lds16_cg(gp + off + lane * 16, lb + off);
        }
      }
      if (v2) {
        const char* gp = (const char*)(hbuf + ((size_t)(4 + ((s - 3) & 1)) * TB + b_base) * TH);
        char* lb = (char*)lds + H2_OFF * 4;
#pragma unroll
        for (int i = 0; i < 4; ++i) {
          int off = wv * 4096 + i * 1024;
          gload_lds16_cg(gp + off + lane * 16, lb + off);
        }
      }
      if (vc) {   // 8 timesteps of x for (b,c) pairs e0=tid, e1=tid+512 (plain cached)
        const int e0 = tid, e1 = tid + NTHR;
        const float* q0 = x + (size_t)(b_base + (e0 >> 6)) * (TC * TT) + (size_t)(e0 & 63) * TT + s;
        const float* q1 = x + (size_t)(b_base + (e1 >> 6)) * (TC * TT) + (size_t)(e1 & 63) * TT + s;
        float4 xa0 = *(const float4*)(q0), xa1 = *(const float4*)(q0 + 4);
        float4 xb0 = *(const float4*)(q1), xb1 = *(const float4*)(q1 + 4);
        float* d0 = lds + X_OFF + (e0 >> 6) * 64 + (e0 & 63);
        float* d1 = lds + X_OFF + (e1 >> 6) * 64 + (e1 & 63);
        d0[0 * 1024] = xa0.x; d0[1 * 1024] = xa0.y; d0[2 * 1024] = xa0.z; d0[3 * 1024] = xa0.w;
        d0[4 * 1024] = xa1.x; d0[5 * 1024] = xa1.y; d0[6 * 1024] = xa1.z; d0[7 * 1024] = xa1.w;
        d1[0 * 1024] = xb0.x; d1[1 * 1024] = xb0.y; d1[2 * 1024] = xb0.z; d1[3 * 1024] = xb0.w;
        d1[4 * 1024] = xb1.x; d1[5 * 1024] = xb1.y; d1[6 * 1024] = xb1.z; d1[7 * 1024] = xb1.w;
      }
    }
    __syncthreads();

    // ---------- compute: 2 passes of 8 batches ----------
#pragma unroll
    for (int p = 0; p < 2; ++p) {
      float a0[8], a1[8], a2[8];
#pragma unroll
      for (int b = 0; b < 8; ++b) { a0[b] = 0.f; a1[b] = 0.f; a2[b] = 0.f; }
#pragma unroll
      for (int b = 0; b < 8; ++b) {
        const int bb = p * 8 + b;
        if (s <= 999) {
          float4 xf = *(const float4*)(lds + X_OFF + (s & 7) * 1024 + bb * 64 + 4 * kk);
          dot4(a0[b], wx, xf);
        }
        if (s >= 1 && s <= 1000) {
          const float* hb = lds + H0_OFF + bb * TH + 32 * kk;
#pragma unroll
          for (int c4 = 0; c4 < 2; ++c4) {
            float4 f0 = *(const float4*)(hb + 16 * c4 + 0);
            float4 f1 = *(const float4*)(hb + 16 * c4 + 4);
            float4 f2 = *(const float4*)(hb + 16 * c4 + 8);
            float4 f3 = *(const float4*)(hb + 16 * c4 + 12);
            if (s <= 999) {
              dot4(a0[b], wh0[4 * c4 + 0], f0); dot4(a0[b], wh0[4 * c4 + 1], f1);
              dot4(a0[b], wh0[4 * c4 + 2], f2); dot4(a0[b], wh0[4 * c4 + 3], f3);
            }
            dot4(a1[b], w1a[4 * c4 + 0], f0); dot4(a1[b], w1a[4 * c4 + 1], f1);
            dot4(a1[b], w1a[4 * c4 + 2], f2); dot4(a1[b], w1a[4 * c4 + 3], f3);
          }
        }
        if (s >= 2) {
          const float* hb = lds + H1_OFF + bb * TH + 32 * kk;
#pragma unroll
          for (int c4 = 0; c4 < 2; ++c4) {
            float4 f0 = *(const float4*)(hb + 16 * c4 + 0);
            float4 f1 = *(const float4*)(hb + 16 * c4 + 4);
            float4 f2 = *(const float4*)(hb + 16 * c4 + 8);
            float4 f3 = *(const float4*)(hb + 16 * c4 + 12);
            if (s <= 1000) {
              dot4(a1[b], w1b[4 * c4 + 0], f0); dot4(a1[b], w1b[4 * c4 + 1], f1);
              dot4(a1[b], w1b[4 * c4 + 2], f2); dot4(a1[b], w1b[4 * c4 + 3], f3);
            }
            dot4(a2[b], w2a[4 * c4 + 0], f0); dot4(a2[b], w2a[4 * c4 + 1], f1);
            dot4(a2[b], w2a[4 * c4 + 2], f2); dot4(a2[b], w2a[4 * c4 + 3], f3);
          }
        }
        if (s >= 3) {
          const float* hb = lds + H2_OFF + bb * TH + 32 * kk;
#pragma unroll
          for (int c4 = 0; c4 < 2; ++c4) {
            float4 f0 = *(const float4*)(hb + 16 * c4 + 0);
            float4 f1 = *(const float4*)(hb + 16 * c4 + 4);
            float4 f2 = *(const float4*)(hb + 16 * c4 + 8);
            float4 f3 = *(const float4*)(hb + 16 * c4 + 12);
            dot4(a2[b], w2b[4 * c4 + 0], f0); dot4(a2[b], w2b[4 * c4 + 1], f1);
            dot4(a2[b], w2b[4 * c4 + 2], f2); dot4(a2[b], w2b[4 * c4 + 3], f3);
          }
        }
      }
      // kk-pair reduce (lane ^ 32), then LDS scratch (conflict-free stride 36)
#pragma unroll
      for (int b = 0; b < 8; ++b) {
        a0[b] += __shfl_xor(a0[b], 32, 64);
        a1[b] += __shfl_xor(a1[b], 32, 64);
        a2[b] += __shfl_xor(a2[b], 32, 64);
      }
      if ((tid & 32) == 0) {
        float* sb = lds + SC_OFF + wv * SC_W + cl * 36 + g;
#pragma unroll
        for (int b = 0; b < 8; ++b) {
          sb[4 * b]       = a0[b];
          sb[288 + 4 * b] = a1[b];
          sb[576 + 4 * b] = a2[b];
        }
      }
      __syncthreads();
      if (tid < 192) {
        const int tl = s - rl;
        if (tl >= 0 && tl < TT) {
          float sx = 0.f, sy = 0.f, sz = 0.f, sw = 0.f;
          const float* sb = lds + SC_OFF + rl * 288 + rc * 36 + 4 * rb;
#pragma unroll
          for (int w8 = 0; w8 < 8; ++w8) {
            float4 v = *(const float4*)(sb + w8 * SC_W);
            sx += v.x; sy += v.y; sz += v.z; sw += v.w;
          }
          float ii = sigf(sx + bias_r.x);
          float ff = sigf(sy + bias_r.y);
          float gg = tanhf(sz + bias_r.z);
          float oo = sigf(sw + bias_r.w);
          float cprev = p ? cst1 : cst0;
          float cc = (tl == 0) ? ii * gg : fmaf(ff, cprev, ii * gg);
          if (p) cst1 = cc; else cst0 = cc;
          float hh = oo * tanhf(cc);
          hbuf[((size_t)(rl * 2 + (tl & 1)) * TB + b_base + p * 8 + rb) * TH + rcell] = hh;
        }
      }
      // p==0: protect scratch before pass-1 writes. p==1: group_barrier's
      // entry __syncthreads covers it (ROUND-20: redundant sync elided).
      if (p == 0) __syncthreads();
    }
    group_barrier(gb, s, xcc, occ_mine, nxcd);
  }
}

__global__ void fc_kernel(const float* __restrict__ hbuf, const float* __restrict__ Wfc,
                          const float* __restrict__ bfc, float* __restrict__ out) {
  int bb = blockIdx.x, lane = threadIdx.x;
  const float* h = hbuf + ((size_t)5 * TB + bb) * TH;   // layer2, parity (999&1)=1
  for (int n = 0; n < NCLS; ++n) {
    float s = 0.f;
    for (int k = lane; k < TH; k += 64) s = fmaf(h[k], Wfc[n * TH + k], s);
    for (int off = 32; off > 0; off >>= 1) s += __shfl_down(s, off, 64);
    if (lane == 0) out[bb * NCLS + n] = s + bfc[n];
  }
}

extern "C" void kernel_launch(void* const* d_in, const int* in_sizes, int n_in,
                              void* d_out, int out_size, void* d_ws, size_t ws_size,
                              hipStream_t stream) {
  const float* x    = (const float*)d_in[0];
  const float* Wih0 = (const float*)d_in[1];
  const float* WihR = (const float*)d_in[2];
  const float* Whh  = (const float*)d_in[3];
  const float* bih  = (const float*)d_in[4];
  const float* bhh  = (const float*)d_in[5];
  const float* Wfc  = (const float*)d_in[6];
  const float* bfc  = (const float*)d_in[7];
  float* out = (float*)d_out;

  char* ws = (char*)d_ws;
  int*   bar  = (int*)ws;                             // 1 KB: 4 groups x 64 ints
  float* hbuf = (float*)(ws + 1024);                  // [3][2][64][512] = 768 KB
  // total d_ws use: 769 KB

  hipMemsetAsync(bar, 0, 1024, stream);
  lstm_pipe<<<256, NTHR, 0, stream>>>(x, Wih0, WihR, Whh, bih, bhh, hbuf, bar);
  fc_kernel<<<TB, 64, 0, stream>>>(hbuf, Wfc, bfc, out);
}